// Round 1
// baseline (1593.612 us; speedup 1.0000x reference)
//
#include <hip/hip_runtime.h>

static __device__ __forceinline__ float relu_f(float v) { return fmaxf(v, 0.f); }

// K1: per 64-node tile: xW = x @ MK (store raw), out[:,64:128] = relu(x @ SK + bias[64:])
__global__ __launch_bounds__(256) void k_node_dual_gemm(
    const float* __restrict__ x, const float* __restrict__ mk,
    const float* __restrict__ sk, const float* __restrict__ bias,
    float* __restrict__ xw, float* __restrict__ out, int n_nodes)
{
  __shared__ float s_mk[64][64];   // 16 KB
  __shared__ float s_sk[64][64];   // 16 KB
  __shared__ float s_xT[64][68];   // transposed x tile, pad 68 to break bank conflicts; 17 KB
  const int tid = threadIdx.x;
  for (int i = tid; i < 4096; i += 256) {
    s_mk[i >> 6][i & 63] = mk[i];
    s_sk[i >> 6][i & 63] = sk[i];
  }
  const int node0 = blockIdx.x * 64;
  for (int i = tid; i < 4096; i += 256) {
    int nl = i >> 6, f = i & 63;
    int n = node0 + nl;
    s_xT[f][nl] = (n < n_nodes) ? x[(size_t)n * 64 + f] : 0.f;
  }
  __syncthreads();
  const int g  = tid >> 4;         // node group: nodes 4g..4g+3
  const int ub = (tid & 15) * 4;   // output quad base
  float am[4][4] = {{0.f}};
  float as[4][4] = {{0.f}};
  for (int f = 0; f < 64; ++f) {
    float4 wm = *(const float4*)&s_mk[f][ub];
    float4 ws = *(const float4*)&s_sk[f][ub];
    float4 xv = *(const float4*)&s_xT[f][4 * g];
    const float xs[4] = {xv.x, xv.y, xv.z, xv.w};
#pragma unroll
    for (int j = 0; j < 4; ++j) {
      am[j][0] += xs[j] * wm.x; am[j][1] += xs[j] * wm.y;
      am[j][2] += xs[j] * wm.z; am[j][3] += xs[j] * wm.w;
      as[j][0] += xs[j] * ws.x; as[j][1] += xs[j] * ws.y;
      as[j][2] += xs[j] * ws.z; as[j][3] += xs[j] * ws.w;
    }
  }
  float4 bv = *(const float4*)&bias[64 + ub];
#pragma unroll
  for (int j = 0; j < 4; ++j) {
    int n = node0 + 4 * g + j;
    if (n >= n_nodes) break;
    float4 o1 = make_float4(am[j][0], am[j][1], am[j][2], am[j][3]);
    *(float4*)&xw[(size_t)n * 64 + ub] = o1;
    float4 o2 = make_float4(relu_f(as[j][0] + bv.x), relu_f(as[j][1] + bv.y),
                            relu_f(as[j][2] + bv.z), relu_f(as[j][3] + bv.w));
    *(float4*)&out[(size_t)n * 128 + 64 + ub] = o2;
  }
}

// K3: per (edge, feature-quad): h = relu(w * xW[col] + mb); atomicAdd into seg[row]; count.
__global__ __launch_bounds__(256) void k_edge_scatter(
    const int* __restrict__ row, const int* __restrict__ col,
    const float* __restrict__ ew, const float* __restrict__ xw,
    const float* __restrict__ mb,
    float* __restrict__ seg, float* __restrict__ cnt, int n_edges)
{
  unsigned t = blockIdx.x * 256u + threadIdx.x;
  unsigned e = t >> 4;
  int q = t & 15;
  if (e >= (unsigned)n_edges) return;
  int r = row[e], c = col[e];
  float we = ew[e];
  float4 v = *(const float4*)&xw[(size_t)c * 64 + 4 * q];
  float4 b = *(const float4*)&mb[4 * q];
  float4 h = make_float4(relu_f(we * v.x + b.x), relu_f(we * v.y + b.y),
                         relu_f(we * v.z + b.z), relu_f(we * v.w + b.w));
  float* s = &seg[(size_t)r * 64 + 4 * q];
  atomicAdd(s + 0, h.x);
  atomicAdd(s + 1, h.y);
  atomicAdd(s + 2, h.z);
  atomicAdd(s + 3, h.w);
  if (q == 0) atomicAdd(&cnt[r], 1.0f);
}

// K4: out[:,0:64] = relu((seg / max(cnt,1)) @ NK + bias[:64])
__global__ __launch_bounds__(256) void k_out_gemm(
    const float* __restrict__ seg, const float* __restrict__ cnt,
    const float* __restrict__ nk, const float* __restrict__ bias,
    float* __restrict__ out, int n_nodes)
{
  __shared__ float s_nk[64][64];
  __shared__ float s_rT[64][68];
  const int tid = threadIdx.x;
  for (int i = tid; i < 4096; i += 256) s_nk[i >> 6][i & 63] = nk[i];
  const int node0 = blockIdx.x * 64;
  for (int i = tid; i < 4096; i += 256) {
    int nl = i >> 6, f = i & 63;
    int n = node0 + nl;
    float v = 0.f;
    if (n < n_nodes) {
      float inv = 1.0f / fmaxf(cnt[n], 1.0f);
      v = seg[(size_t)n * 64 + f] * inv;
    }
    s_rT[f][nl] = v;
  }
  __syncthreads();
  const int g  = tid >> 4;
  const int ub = (tid & 15) * 4;
  float ac[4][4] = {{0.f}};
  for (int f = 0; f < 64; ++f) {
    float4 w  = *(const float4*)&s_nk[f][ub];
    float4 xv = *(const float4*)&s_rT[f][4 * g];
    const float xs[4] = {xv.x, xv.y, xv.z, xv.w};
#pragma unroll
    for (int j = 0; j < 4; ++j) {
      ac[j][0] += xs[j] * w.x; ac[j][1] += xs[j] * w.y;
      ac[j][2] += xs[j] * w.z; ac[j][3] += xs[j] * w.w;
    }
  }
  float4 bv = *(const float4*)&bias[ub];
#pragma unroll
  for (int j = 0; j < 4; ++j) {
    int n = node0 + 4 * g + j;
    if (n >= n_nodes) break;
    float4 o = make_float4(relu_f(ac[j][0] + bv.x), relu_f(ac[j][1] + bv.y),
                           relu_f(ac[j][2] + bv.z), relu_f(ac[j][3] + bv.w));
    *(float4*)&out[(size_t)n * 128 + ub] = o;
  }
}

extern "C" void kernel_launch(void* const* d_in, const int* in_sizes, int n_in,
                              void* d_out, int out_size, void* d_ws, size_t ws_size,
                              hipStream_t stream) {
  const float* x    = (const float*)d_in[0];
  const int*   ei   = (const int*)d_in[1];     // [2, E]: row = ei[0:E], col = ei[E:2E]
  const float* ew   = (const float*)d_in[2];
  const float* mk   = (const float*)d_in[3];
  const float* mb   = (const float*)d_in[4];
  const float* nk   = (const float*)d_in[5];
  const float* sk   = (const float*)d_in[6];
  const float* bias = (const float*)d_in[7];
  float* out = (float*)d_out;

  const int n_nodes = in_sizes[0] / 64;
  const int n_edges = in_sizes[2];

  float* xw  = (float*)d_ws;                    // [N, 64]
  float* seg = xw  + (size_t)n_nodes * 64;      // [N, 64]
  float* cnt = seg + (size_t)n_nodes * 64;      // [N]

  // zero seg + cnt (contiguous)
  hipMemsetAsync(seg, 0, ((size_t)n_nodes * 64 + (size_t)n_nodes) * sizeof(float), stream);

  const int nbn = (n_nodes + 63) / 64;
  k_node_dual_gemm<<<nbn, 256, 0, stream>>>(x, mk, sk, bias, xw, out, n_nodes);

  const unsigned nbe = (unsigned)(((long long)n_edges * 16 + 255) / 256);
  k_edge_scatter<<<nbe, 256, 0, stream>>>(ei, ei + n_edges, ew, xw, mb, seg, cnt, n_edges);

  k_out_gemm<<<nbn, 256, 0, stream>>>(seg, cnt, nk, bias, out, n_nodes);
}

// Round 2
// 430.409 us; speedup vs baseline: 3.7025x; 3.7025x over previous
//
#include <hip/hip_runtime.h>

static __device__ __forceinline__ float relu_f(float v) { return fmaxf(v, 0.f); }

// K1: per 64-node tile: xW = x @ MK (store raw), out[:,64:128] = relu(x @ SK + bias[64:])
__global__ __launch_bounds__(256) void k_node_dual_gemm(
    const float* __restrict__ x, const float* __restrict__ mk,
    const float* __restrict__ sk, const float* __restrict__ bias,
    float* __restrict__ xw, float* __restrict__ out, int n_nodes)
{
  __shared__ float s_mk[64][64];
  __shared__ float s_sk[64][64];
  __shared__ float s_xT[64][68];
  const int tid = threadIdx.x;
  for (int i = tid; i < 4096; i += 256) {
    s_mk[i >> 6][i & 63] = mk[i];
    s_sk[i >> 6][i & 63] = sk[i];
  }
  const int node0 = blockIdx.x * 64;
  for (int i = tid; i < 4096; i += 256) {
    int nl = i >> 6, f = i & 63;
    int n = node0 + nl;
    s_xT[f][nl] = (n < n_nodes) ? x[(size_t)n * 64 + f] : 0.f;
  }
  __syncthreads();
  const int g  = tid >> 4;
  const int ub = (tid & 15) * 4;
  float am[4][4] = {{0.f}};
  float as[4][4] = {{0.f}};
  for (int f = 0; f < 64; ++f) {
    float4 wm = *(const float4*)&s_mk[f][ub];
    float4 ws = *(const float4*)&s_sk[f][ub];
    float4 xv = *(const float4*)&s_xT[f][4 * g];
    const float xs[4] = {xv.x, xv.y, xv.z, xv.w};
#pragma unroll
    for (int j = 0; j < 4; ++j) {
      am[j][0] += xs[j] * wm.x; am[j][1] += xs[j] * wm.y;
      am[j][2] += xs[j] * wm.z; am[j][3] += xs[j] * wm.w;
      as[j][0] += xs[j] * ws.x; as[j][1] += xs[j] * ws.y;
      as[j][2] += xs[j] * ws.z; as[j][3] += xs[j] * ws.w;
    }
  }
  float4 bv = *(const float4*)&bias[64 + ub];
#pragma unroll
  for (int j = 0; j < 4; ++j) {
    int n = node0 + 4 * g + j;
    if (n >= n_nodes) break;
    *(float4*)&xw[(size_t)n * 64 + ub] =
        make_float4(am[j][0], am[j][1], am[j][2], am[j][3]);
    *(float4*)&out[(size_t)n * 128 + 64 + ub] =
        make_float4(relu_f(as[j][0] + bv.x), relu_f(as[j][1] + bv.y),
                    relu_f(as[j][2] + bv.z), relu_f(as[j][3] + bv.w));
  }
}

// Count in-degree per destination node (int atomics).
__global__ __launch_bounds__(256) void k_count(
    const int* __restrict__ row, int* __restrict__ cnt, int n_edges)
{
  int e = blockIdx.x * 256 + threadIdx.x;
  if (e < n_edges) atomicAdd(&cnt[row[e]], 1);
}

// Scan step 1: per-1024-block sums of cnt.
__global__ __launch_bounds__(1024) void k_bsum(
    const int* __restrict__ cnt, int* __restrict__ bsum, int n)
{
  __shared__ int s[1024];
  int tid = threadIdx.x;
  int i = blockIdx.x * 1024 + tid;
  s[tid] = (i < n) ? cnt[i] : 0;
  __syncthreads();
  for (int d = 512; d > 0; d >>= 1) {
    if (tid < d) s[tid] += s[tid + d];
    __syncthreads();
  }
  if (tid == 0) bsum[blockIdx.x] = s[0];
}

// Scan step 2: exclusive scan of block sums (tiny; single thread).
__global__ void k_btop(int* __restrict__ bsum, int nb)
{
  if (threadIdx.x == 0 && blockIdx.x == 0) {
    int run = 0;
    for (int j = 0; j < nb; ++j) { int t = bsum[j]; bsum[j] = run; run += t; }
  }
}

// Scan step 3: block-local exclusive scan + block offset -> off[] (start offsets).
__global__ __launch_bounds__(1024) void k_boffs(
    const int* __restrict__ cnt, const int* __restrict__ bsum,
    int* __restrict__ off, int n)
{
  __shared__ int s[1024];
  int tid = threadIdx.x;
  int i = blockIdx.x * 1024 + tid;
  int v = (i < n) ? cnt[i] : 0;
  s[tid] = v;
  __syncthreads();
  for (int d = 1; d < 1024; d <<= 1) {
    int t = (tid >= d) ? s[tid - d] : 0;
    __syncthreads();
    s[tid] += t;
    __syncthreads();
  }
  if (i < n) off[i] = s[tid] - v + bsum[blockIdx.x];
}

// Build edge list: elist[pos] = {col, weight_bits}; off[] becomes end[].
__global__ __launch_bounds__(256) void k_build(
    const int* __restrict__ row, const int* __restrict__ col,
    const float* __restrict__ ew, int* __restrict__ off,
    int2* __restrict__ elist, int n_edges)
{
  int e = blockIdx.x * 256 + threadIdx.x;
  if (e >= n_edges) return;
  int r = row[e];
  int pos = atomicAdd(&off[r], 1);
  elist[pos] = make_int2(col[e], __float_as_int(ew[e]));
}

// Fused: per-node mean of relu(w*xW[col]+mb) over edge list, then @nk + bias + relu.
// 16 nodes/block, 16 lanes/node (lane handles feature quad q).
__global__ __launch_bounds__(256) void k_fused_reduce_gemm(
    const int* __restrict__ cnt, const int* __restrict__ off,
    const int2* __restrict__ elist, const float* __restrict__ xw,
    const float* __restrict__ mb, const float* __restrict__ nk,
    const float* __restrict__ bias, float* __restrict__ out, int n_nodes)
{
  __shared__ float s_nk[64][64];   // 16 KB
  __shared__ float s_rh[16][68];   // padded
  const int tid = threadIdx.x;
  for (int i = tid; i < 1024; i += 256) {
    *(float4*)&s_nk[0][4 * i] = *(const float4*)&nk[4 * i];
  }
  const int node_l = tid >> 4;
  const int q = tid & 15;
  const int n = blockIdx.x * 16 + node_l;
  float4 acc = make_float4(0.f, 0.f, 0.f, 0.f);
  if (n < n_nodes) {
    const float4 mbq = *(const float4*)&mb[4 * q];
    const int c = cnt[n];
    const int end = off[n];        // after k_build, off[n] == end
    const int start = end - c;
    for (int i = start; i < end; ++i) {
      int2 ecw = elist[i];
      float w = __int_as_float(ecw.y);
      float4 v = *(const float4*)&xw[(size_t)ecw.x * 64 + 4 * q];
      acc.x += relu_f(w * v.x + mbq.x);
      acc.y += relu_f(w * v.y + mbq.y);
      acc.z += relu_f(w * v.z + mbq.z);
      acc.w += relu_f(w * v.w + mbq.w);
    }
    const float inv = 1.0f / fmaxf((float)c, 1.0f);
    acc.x *= inv; acc.y *= inv; acc.z *= inv; acc.w *= inv;
  }
  *(float4*)&s_rh[node_l][4 * q] = acc;
  __syncthreads();
  float4 o = make_float4(0.f, 0.f, 0.f, 0.f);
  for (int f = 0; f < 64; ++f) {
    float rv = s_rh[node_l][f];
    float4 wv = *(const float4*)&s_nk[f][4 * q];
    o.x += rv * wv.x; o.y += rv * wv.y; o.z += rv * wv.z; o.w += rv * wv.w;
  }
  if (n < n_nodes) {
    float4 bv = *(const float4*)&bias[4 * q];
    *(float4*)&out[(size_t)n * 128 + 4 * q] =
        make_float4(relu_f(o.x + bv.x), relu_f(o.y + bv.y),
                    relu_f(o.z + bv.z), relu_f(o.w + bv.w));
  }
}

extern "C" void kernel_launch(void* const* d_in, const int* in_sizes, int n_in,
                              void* d_out, int out_size, void* d_ws, size_t ws_size,
                              hipStream_t stream) {
  const float* x    = (const float*)d_in[0];
  const int*   ei   = (const int*)d_in[1];     // [2, E]
  const float* ew   = (const float*)d_in[2];
  const float* mk   = (const float*)d_in[3];
  const float* mb   = (const float*)d_in[4];
  const float* nk   = (const float*)d_in[5];
  const float* sk   = (const float*)d_in[6];
  const float* bias = (const float*)d_in[7];
  float* out = (float*)d_out;

  const int n_nodes = in_sizes[0] / 64;
  const int n_edges = in_sizes[2];
  const int* row = ei;
  const int* col = ei + n_edges;

  // ws layout
  float* xw   = (float*)d_ws;                          // [N,64]
  int*   cnt  = (int*)(xw + (size_t)n_nodes * 64);     // [N]
  int*   off  = cnt + n_nodes;                         // [N]
  int*   bsum = off + n_nodes;                         // [128]
  int2*  elist = (int2*)(((char*)(bsum + 128)) );      // [E]

  const int nb_scan = (n_nodes + 1023) / 1024;

  hipMemsetAsync(cnt, 0, (size_t)n_nodes * sizeof(int), stream);

  const int nbn = (n_nodes + 63) / 64;
  k_node_dual_gemm<<<nbn, 256, 0, stream>>>(x, mk, sk, bias, xw, out, n_nodes);

  const int nbe = (n_edges + 255) / 256;
  k_count<<<nbe, 256, 0, stream>>>(row, cnt, n_edges);
  k_bsum<<<nb_scan, 1024, 0, stream>>>(cnt, bsum, n_nodes);
  k_btop<<<1, 64, 0, stream>>>(bsum, nb_scan);
  k_boffs<<<nb_scan, 1024, 0, stream>>>(cnt, bsum, off, n_nodes);
  k_build<<<nbe, 256, 0, stream>>>(row, col, ew, off, elist, n_edges);

  const int nbf = (n_nodes + 15) / 16;
  k_fused_reduce_gemm<<<nbf, 256, 0, stream>>>(cnt, off, elist, xw, mb, nk, bias,
                                               out, n_nodes);
}

// Round 3
// 387.414 us; speedup vs baseline: 4.1135x; 1.1110x over previous
//
#include <hip/hip_runtime.h>

static __device__ __forceinline__ float relu_f(float v) { return fmaxf(v, 0.f); }

// K1: per 64-node tile: xW = x @ MK (store raw), out[:,64:128] = relu(x @ SK + bias[64:])
__global__ __launch_bounds__(256) void k_node_dual_gemm(
    const float* __restrict__ x, const float* __restrict__ mk,
    const float* __restrict__ sk, const float* __restrict__ bias,
    float* __restrict__ xw, float* __restrict__ out, int n_nodes)
{
  __shared__ float s_mk[64][64];
  __shared__ float s_sk[64][64];
  __shared__ float s_xT[64][68];
  const int tid = threadIdx.x;
  for (int i = tid; i < 4096; i += 256) {
    s_mk[i >> 6][i & 63] = mk[i];
    s_sk[i >> 6][i & 63] = sk[i];
  }
  const int node0 = blockIdx.x * 64;
  for (int i = tid; i < 4096; i += 256) {
    int nl = i >> 6, f = i & 63;
    int n = node0 + nl;
    s_xT[f][nl] = (n < n_nodes) ? x[(size_t)n * 64 + f] : 0.f;
  }
  __syncthreads();
  const int g  = tid >> 4;
  const int ub = (tid & 15) * 4;
  float am[4][4] = {{0.f}};
  float as[4][4] = {{0.f}};
  for (int f = 0; f < 64; ++f) {
    float4 wm = *(const float4*)&s_mk[f][ub];
    float4 ws = *(const float4*)&s_sk[f][ub];
    float4 xv = *(const float4*)&s_xT[f][4 * g];
    const float xs[4] = {xv.x, xv.y, xv.z, xv.w};
#pragma unroll
    for (int j = 0; j < 4; ++j) {
      am[j][0] += xs[j] * wm.x; am[j][1] += xs[j] * wm.y;
      am[j][2] += xs[j] * wm.z; am[j][3] += xs[j] * wm.w;
      as[j][0] += xs[j] * ws.x; as[j][1] += xs[j] * ws.y;
      as[j][2] += xs[j] * ws.z; as[j][3] += xs[j] * ws.w;
    }
  }
  float4 bv = *(const float4*)&bias[64 + ub];
#pragma unroll
  for (int j = 0; j < 4; ++j) {
    int n = node0 + 4 * g + j;
    if (n >= n_nodes) break;
    *(float4*)&xw[(size_t)n * 64 + ub] =
        make_float4(am[j][0], am[j][1], am[j][2], am[j][3]);
    *(float4*)&out[(size_t)n * 128 + 64 + ub] =
        make_float4(relu_f(as[j][0] + bv.x), relu_f(as[j][1] + bv.y),
                    relu_f(as[j][2] + bv.z), relu_f(as[j][3] + bv.w));
  }
}

// Count in-degree per destination node (int atomics, L2-resident).
__global__ __launch_bounds__(256) void k_count(
    const int* __restrict__ row, int* __restrict__ cnt, int n_edges)
{
  int e = blockIdx.x * 256 + threadIdx.x;
  if (e < n_edges) atomicAdd(&cnt[row[e]], 1);
}

// Scan step 1: per-1024-block sums of cnt.
__global__ __launch_bounds__(1024) void k_bsum(
    const int* __restrict__ cnt, int* __restrict__ bsum, int n)
{
  __shared__ int s[1024];
  int tid = threadIdx.x;
  int i = blockIdx.x * 1024 + tid;
  s[tid] = (i < n) ? cnt[i] : 0;
  __syncthreads();
  for (int d = 512; d > 0; d >>= 1) {
    if (tid < d) s[tid] += s[tid + d];
    __syncthreads();
  }
  if (tid == 0) bsum[blockIdx.x] = s[0];
}

// Scan step 2: exclusive scan of block sums (tiny; single thread).
__global__ void k_btop(int* __restrict__ bsum, int nb)
{
  if (threadIdx.x == 0 && blockIdx.x == 0) {
    int run = 0;
    for (int j = 0; j < nb; ++j) { int t = bsum[j]; bsum[j] = run; run += t; }
  }
}

// Scan step 3: block-local exclusive scan + block offset -> off[] (start offsets).
__global__ __launch_bounds__(1024) void k_boffs(
    const int* __restrict__ cnt, const int* __restrict__ bsum,
    int* __restrict__ off, int n)
{
  __shared__ int s[1024];
  int tid = threadIdx.x;
  int i = blockIdx.x * 1024 + tid;
  int v = (i < n) ? cnt[i] : 0;
  s[tid] = v;
  __syncthreads();
  for (int d = 1; d < 1024; d <<= 1) {
    int t = (tid >= d) ? s[tid - d] : 0;
    __syncthreads();
    s[tid] += t;
    __syncthreads();
  }
  if (i < n) off[i] = s[tid] - v + bsum[blockIdx.x];
}

// XCD-sliced CSR build: slice s = blockIdx & 7 owns rows [s*sliceN, (s+1)*sliceN).
// Each slice-group grid-strides over ALL edges, claiming only its rows, so each
// XCD's elist write window is ~1.6 MB (L2-resident -> full-line merged writes).
__global__ __launch_bounds__(256) void k_build_sliced(
    const int* __restrict__ row, const int* __restrict__ col,
    const float* __restrict__ ew, int* __restrict__ off,
    int2* __restrict__ elist, int n_edges, int n_nodes)
{
  const int slice = blockIdx.x & 7;
  const int vb    = blockIdx.x >> 3;
  const int nvb   = gridDim.x >> 3;
  const int sliceN = (n_nodes + 7) >> 3;
  const int lo = slice * sliceN;
  const int hi = min(lo + sliceN, n_nodes);
  for (int e = vb * 256 + threadIdx.x; e < n_edges; e += nvb * 256) {
    int r = row[e];
    if (r >= lo && r < hi) {
      int pos = atomicAdd(&off[r], 1);
      elist[pos] = make_int2(col[e], __float_as_int(ew[e]));
    }
  }
}

// Fused: per-node mean of relu(w*xW[col]+mb) over edge list, then @nk + bias + relu.
// 16 nodes/block, 16 lanes/node (lane handles feature quad q).
__global__ __launch_bounds__(256) void k_fused_reduce_gemm(
    const int* __restrict__ cnt, const int* __restrict__ off,
    const int2* __restrict__ elist, const float* __restrict__ xw,
    const float* __restrict__ mb, const float* __restrict__ nk,
    const float* __restrict__ bias, float* __restrict__ out, int n_nodes)
{
  __shared__ float s_nk[64][64];
  __shared__ float s_rh[16][68];
  const int tid = threadIdx.x;
  for (int i = tid; i < 1024; i += 256) {
    *(float4*)&s_nk[0][4 * i] = *(const float4*)&nk[4 * i];
  }
  const int node_l = tid >> 4;
  const int q = tid & 15;
  const int n = blockIdx.x * 16 + node_l;
  float4 acc = make_float4(0.f, 0.f, 0.f, 0.f);
  if (n < n_nodes) {
    const float4 mbq = *(const float4*)&mb[4 * q];
    const int c = cnt[n];
    const int end = off[n];        // after build, off[n] == end
    const int start = end - c;
    for (int i = start; i < end; ++i) {
      int2 ecw = elist[i];
      float w = __int_as_float(ecw.y);
      float4 v = *(const float4*)&xw[(size_t)ecw.x * 64 + 4 * q];
      acc.x += relu_f(w * v.x + mbq.x);
      acc.y += relu_f(w * v.y + mbq.y);
      acc.z += relu_f(w * v.z + mbq.z);
      acc.w += relu_f(w * v.w + mbq.w);
    }
    const float inv = 1.0f / fmaxf((float)c, 1.0f);
    acc.x *= inv; acc.y *= inv; acc.z *= inv; acc.w *= inv;
  }
  *(float4*)&s_rh[node_l][4 * q] = acc;
  __syncthreads();
  float4 o = make_float4(0.f, 0.f, 0.f, 0.f);
  for (int f = 0; f < 64; ++f) {
    float rv = s_rh[node_l][f];
    float4 wv = *(const float4*)&s_nk[f][4 * q];
    o.x += rv * wv.x; o.y += rv * wv.y; o.z += rv * wv.z; o.w += rv * wv.w;
  }
  if (n < n_nodes) {
    float4 bv = *(const float4*)&bias[4 * q];
    *(float4*)&out[(size_t)n * 128 + 4 * q] =
        make_float4(relu_f(o.x + bv.x), relu_f(o.y + bv.y),
                    relu_f(o.z + bv.z), relu_f(o.w + bv.w));
  }
}

extern "C" void kernel_launch(void* const* d_in, const int* in_sizes, int n_in,
                              void* d_out, int out_size, void* d_ws, size_t ws_size,
                              hipStream_t stream) {
  const float* x    = (const float*)d_in[0];
  const int*   ei   = (const int*)d_in[1];     // [2, E]
  const float* ew   = (const float*)d_in[2];
  const float* mk   = (const float*)d_in[3];
  const float* mb   = (const float*)d_in[4];
  const float* nk   = (const float*)d_in[5];
  const float* sk   = (const float*)d_in[6];
  const float* bias = (const float*)d_in[7];
  float* out = (float*)d_out;

  const int n_nodes = in_sizes[0] / 64;
  const int n_edges = in_sizes[2];
  const int* row = ei;
  const int* col = ei + n_edges;

  // ws layout
  float* xw   = (float*)d_ws;                          // [N,64]
  int*   cnt  = (int*)(xw + (size_t)n_nodes * 64);     // [N]
  int*   off  = cnt + n_nodes;                         // [N]
  int*   bsum = off + n_nodes;                         // [128]
  int2*  elist = (int2*)((char*)(bsum + 128));         // [E]

  const int nb_scan = (n_nodes + 1023) / 1024;

  hipMemsetAsync(cnt, 0, (size_t)n_nodes * sizeof(int), stream);

  const int nbn = (n_nodes + 63) / 64;
  k_node_dual_gemm<<<nbn, 256, 0, stream>>>(x, mk, sk, bias, xw, out, n_nodes);

  const int nbe = (n_edges + 255) / 256;
  k_count<<<nbe, 256, 0, stream>>>(row, cnt, n_edges);
  k_bsum<<<nb_scan, 1024, 0, stream>>>(cnt, bsum, n_nodes);
  k_btop<<<1, 64, 0, stream>>>(bsum, nb_scan);
  k_boffs<<<nb_scan, 1024, 0, stream>>>(cnt, bsum, off, n_nodes);

  // 1024 blocks = 128 virtual blocks per slice; slice = blockIdx & 7 (XCD heuristic)
  k_build_sliced<<<1024, 256, 0, stream>>>(row, col, ew, off, elist, n_edges, n_nodes);

  const int nbf = (n_nodes + 15) / 16;
  k_fused_reduce_gemm<<<nbf, 256, 0, stream>>>(cnt, off, elist, xw, mb, nk, bias,
                                               out, n_nodes);
}

// Round 4
// 350.839 us; speedup vs baseline: 4.5423x; 1.1043x over previous
//
#include <hip/hip_runtime.h>

static __device__ __forceinline__ float relu_f(float v) { return fmaxf(v, 0.f); }

// fp32 -> bf16 with round-to-nearest-even
static __device__ __forceinline__ unsigned short f2bf(float f) {
  unsigned u = __float_as_uint(f);
  u += 0x7fffu + ((u >> 16) & 1u);
  return (unsigned short)(u >> 16);
}
static __device__ __forceinline__ float bf2f(unsigned short h) {
  return __uint_as_float(((unsigned)h) << 16);
}

// K1: per 64-node tile: xw(bf16) = x @ MK, out[:,64:128] = relu(x @ SK + bias[64:])
__global__ __launch_bounds__(256) void k_node_dual_gemm(
    const float* __restrict__ x, const float* __restrict__ mk,
    const float* __restrict__ sk, const float* __restrict__ bias,
    unsigned short* __restrict__ xwh, float* __restrict__ out, int n_nodes)
{
  __shared__ float s_mk[64][64];
  __shared__ float s_sk[64][64];
  __shared__ float s_xT[64][68];
  const int tid = threadIdx.x;
  for (int i = tid; i < 4096; i += 256) {
    s_mk[i >> 6][i & 63] = mk[i];
    s_sk[i >> 6][i & 63] = sk[i];
  }
  const int node0 = blockIdx.x * 64;
  for (int i = tid; i < 4096; i += 256) {
    int nl = i >> 6, f = i & 63;
    int n = node0 + nl;
    s_xT[f][nl] = (n < n_nodes) ? x[(size_t)n * 64 + f] : 0.f;
  }
  __syncthreads();
  const int g  = tid >> 4;
  const int ub = (tid & 15) * 4;
  float am[4][4] = {{0.f}};
  float as[4][4] = {{0.f}};
  for (int f = 0; f < 64; ++f) {
    float4 wm = *(const float4*)&s_mk[f][ub];
    float4 ws = *(const float4*)&s_sk[f][ub];
    float4 xv = *(const float4*)&s_xT[f][4 * g];
    const float xs[4] = {xv.x, xv.y, xv.z, xv.w};
#pragma unroll
    for (int j = 0; j < 4; ++j) {
      am[j][0] += xs[j] * wm.x; am[j][1] += xs[j] * wm.y;
      am[j][2] += xs[j] * wm.z; am[j][3] += xs[j] * wm.w;
      as[j][0] += xs[j] * ws.x; as[j][1] += xs[j] * ws.y;
      as[j][2] += xs[j] * ws.z; as[j][3] += xs[j] * ws.w;
    }
  }
  float4 bv = *(const float4*)&bias[64 + ub];
#pragma unroll
  for (int j = 0; j < 4; ++j) {
    int n = node0 + 4 * g + j;
    if (n >= n_nodes) break;
    ushort4 o1 = make_ushort4(f2bf(am[j][0]), f2bf(am[j][1]),
                              f2bf(am[j][2]), f2bf(am[j][3]));
    *(ushort4*)&xwh[(size_t)n * 64 + ub] = o1;
    *(float4*)&out[(size_t)n * 128 + 64 + ub] =
        make_float4(relu_f(as[j][0] + bv.x), relu_f(as[j][1] + bv.y),
                    relu_f(as[j][2] + bv.z), relu_f(as[j][3] + bv.w));
  }
}

// Count in-degree per destination node (int atomics, L2-resident).
__global__ __launch_bounds__(256) void k_count(
    const int* __restrict__ row, int* __restrict__ cnt, int n_edges)
{
  int e = blockIdx.x * 256 + threadIdx.x;
  if (e < n_edges) atomicAdd(&cnt[row[e]], 1);
}

// Scan step 1: per-1024-block sums of cnt.
__global__ __launch_bounds__(1024) void k_bsum(
    const int* __restrict__ cnt, int* __restrict__ bsum, int n)
{
  __shared__ int s[1024];
  int tid = threadIdx.x;
  int i = blockIdx.x * 1024 + tid;
  s[tid] = (i < n) ? cnt[i] : 0;
  __syncthreads();
  for (int d = 512; d > 0; d >>= 1) {
    if (tid < d) s[tid] += s[tid + d];
    __syncthreads();
  }
  if (tid == 0) bsum[blockIdx.x] = s[0];
}

// Scan step 2 (fused btop): block-local exclusive scan of cnt; block prefix
// computed by in-block reduction over bsum[0..blockIdx.x-1].
__global__ __launch_bounds__(1024) void k_boffs(
    const int* __restrict__ cnt, const int* __restrict__ bsum,
    int* __restrict__ off, int n, int nb)
{
  __shared__ int s[1024];
  __shared__ int sp[128];
  int tid = threadIdx.x;
  // strided partial sums of bsum[j], j < blockIdx.x
  if (tid < 128) {
    int acc = 0;
    for (int j = tid; j < blockIdx.x && j < nb; j += 128) acc += bsum[j];
    sp[tid] = acc;
  }
  int i = blockIdx.x * 1024 + tid;
  int v = (i < n) ? cnt[i] : 0;
  s[tid] = v;
  __syncthreads();
  for (int d = 64; d > 0; d >>= 1) {
    if (tid < d) sp[tid] += sp[tid + d];
    __syncthreads();
  }
  for (int d = 1; d < 1024; d <<= 1) {
    int t = (tid >= d) ? s[tid - d] : 0;
    __syncthreads();
    s[tid] += t;
    __syncthreads();
  }
  if (i < n) off[i] = s[tid] - v + sp[0];
}

// XCD-sliced CSR build: slice s = blockIdx & 7 owns rows [s*sliceN, (s+1)*sliceN).
__global__ __launch_bounds__(256) void k_build_sliced(
    const int* __restrict__ row, const int* __restrict__ col,
    const float* __restrict__ ew, int* __restrict__ off,
    int2* __restrict__ elist, int n_edges, int n_nodes)
{
  const int slice = blockIdx.x & 7;
  const int vb    = blockIdx.x >> 3;
  const int nvb   = gridDim.x >> 3;
  const int sliceN = (n_nodes + 7) >> 3;
  const int lo = slice * sliceN;
  const int hi = min(lo + sliceN, n_nodes);
  for (int e = vb * 256 + threadIdx.x; e < n_edges; e += nvb * 256) {
    int r = row[e];
    if (r >= lo && r < hi) {
      int pos = atomicAdd(&off[r], 1);
      elist[pos] = make_int2(col[e], __float_as_int(ew[e]));
    }
  }
}

// Fused: per-node mean of relu(w*xw[col]+mb) over edge list, then @nk + bias + relu.
// 16 nodes/block, 16 lanes/node; xw is bf16 (128 B/row), lane reads ushort4 (8 B).
__global__ __launch_bounds__(256) void k_fused_reduce_gemm(
    const int* __restrict__ cnt, const int* __restrict__ off,
    const int2* __restrict__ elist, const unsigned short* __restrict__ xwh,
    const float* __restrict__ mb, const float* __restrict__ nk,
    const float* __restrict__ bias, float* __restrict__ out, int n_nodes)
{
  __shared__ float s_nk[64][64];
  __shared__ float s_rh[16][68];
  const int tid = threadIdx.x;
  for (int i = tid; i < 1024; i += 256) {
    *(float4*)&s_nk[0][4 * i] = *(const float4*)&nk[4 * i];
  }
  const int node_l = tid >> 4;
  const int q = tid & 15;
  const int n = blockIdx.x * 16 + node_l;
  float4 acc = make_float4(0.f, 0.f, 0.f, 0.f);
  if (n < n_nodes) {
    const float4 mbq = *(const float4*)&mb[4 * q];
    const int c = cnt[n];
    const int end = off[n];        // after build, off[n] == end
    int i = end - c;
    for (; i + 2 <= end; i += 2) {
      int2 e0 = elist[i];
      int2 e1 = elist[i + 1];
      ushort4 u0 = *(const ushort4*)&xwh[(size_t)e0.x * 64 + 4 * q];
      ushort4 u1 = *(const ushort4*)&xwh[(size_t)e1.x * 64 + 4 * q];
      float w0 = __int_as_float(e0.y);
      float w1 = __int_as_float(e1.y);
      acc.x += relu_f(w0 * bf2f(u0.x) + mbq.x);
      acc.y += relu_f(w0 * bf2f(u0.y) + mbq.y);
      acc.z += relu_f(w0 * bf2f(u0.z) + mbq.z);
      acc.w += relu_f(w0 * bf2f(u0.w) + mbq.w);
      acc.x += relu_f(w1 * bf2f(u1.x) + mbq.x);
      acc.y += relu_f(w1 * bf2f(u1.y) + mbq.y);
      acc.z += relu_f(w1 * bf2f(u1.z) + mbq.z);
      acc.w += relu_f(w1 * bf2f(u1.w) + mbq.w);
    }
    if (i < end) {
      int2 e0 = elist[i];
      ushort4 u0 = *(const ushort4*)&xwh[(size_t)e0.x * 64 + 4 * q];
      float w0 = __int_as_float(e0.y);
      acc.x += relu_f(w0 * bf2f(u0.x) + mbq.x);
      acc.y += relu_f(w0 * bf2f(u0.y) + mbq.y);
      acc.z += relu_f(w0 * bf2f(u0.z) + mbq.z);
      acc.w += relu_f(w0 * bf2f(u0.w) + mbq.w);
    }
    const float inv = 1.0f / fmaxf((float)c, 1.0f);
    acc.x *= inv; acc.y *= inv; acc.z *= inv; acc.w *= inv;
  }
  *(float4*)&s_rh[node_l][4 * q] = acc;
  __syncthreads();
  float4 o = make_float4(0.f, 0.f, 0.f, 0.f);
  for (int f = 0; f < 64; ++f) {
    float rv = s_rh[node_l][f];
    float4 wv = *(const float4*)&s_nk[f][4 * q];
    o.x += rv * wv.x; o.y += rv * wv.y; o.z += rv * wv.z; o.w += rv * wv.w;
  }
  if (n < n_nodes) {
    float4 bv = *(const float4*)&bias[4 * q];
    *(float4*)&out[(size_t)n * 128 + 4 * q] =
        make_float4(relu_f(o.x + bv.x), relu_f(o.y + bv.y),
                    relu_f(o.z + bv.z), relu_f(o.w + bv.w));
  }
}

extern "C" void kernel_launch(void* const* d_in, const int* in_sizes, int n_in,
                              void* d_out, int out_size, void* d_ws, size_t ws_size,
                              hipStream_t stream) {
  const float* x    = (const float*)d_in[0];
  const int*   ei   = (const int*)d_in[1];     // [2, E]
  const float* ew   = (const float*)d_in[2];
  const float* mk   = (const float*)d_in[3];
  const float* mb   = (const float*)d_in[4];
  const float* nk   = (const float*)d_in[5];
  const float* sk   = (const float*)d_in[6];
  const float* bias = (const float*)d_in[7];
  float* out = (float*)d_out;

  const int n_nodes = in_sizes[0] / 64;
  const int n_edges = in_sizes[2];
  const int* row = ei;
  const int* col = ei + n_edges;

  // ws layout (xwh bf16 first, then ints; elist 8B-aligned)
  unsigned short* xwh = (unsigned short*)d_ws;              // [N*64] bf16
  int*  cnt  = (int*)(xwh + (size_t)n_nodes * 64);
  int*  off  = cnt + n_nodes;
  int*  bsum = off + n_nodes;
  size_t ebytes = ((size_t)(bsum + 128) - (size_t)d_ws + 7) & ~(size_t)7;
  int2* elist = (int2*)((char*)d_ws + ebytes);              // [E]

  const int nb_scan = (n_nodes + 1023) / 1024;

  hipMemsetAsync(cnt, 0, (size_t)n_nodes * sizeof(int), stream);

  const int nbn = (n_nodes + 63) / 64;
  k_node_dual_gemm<<<nbn, 256, 0, stream>>>(x, mk, sk, bias, xwh, out, n_nodes);

  const int nbe = (n_edges + 255) / 256;
  k_count<<<nbe, 256, 0, stream>>>(row, cnt, n_edges);
  k_bsum<<<nb_scan, 1024, 0, stream>>>(cnt, bsum, n_nodes);
  k_boffs<<<nb_scan, 1024, 0, stream>>>(cnt, bsum, off, n_nodes, nb_scan);

  k_build_sliced<<<1024, 256, 0, stream>>>(row, col, ew, off, elist, n_edges, n_nodes);

  const int nbf = (n_nodes + 15) / 16;
  k_fused_reduce_gemm<<<nbf, 256, 0, stream>>>(cnt, off, elist, xwh, mb, nk, bias,
                                               out, n_nodes);
}